// Round 7
// baseline (113.941 us; speedup 1.0000x reference)
//
#include <hip/hip_runtime.h>

typedef __bf16 bf16;
typedef __attribute__((ext_vector_type(8))) __bf16 bf16x8;
typedef __attribute__((ext_vector_type(4))) __bf16 bf16x4;
typedef __attribute__((ext_vector_type(2))) __bf16 bf16x2;
typedef __attribute__((ext_vector_type(4))) float floatx4;

#define MFMA16(a,b,c) __builtin_amdgcn_mfma_f32_16x16x32_bf16((a),(b),(c),0,0,0)

__device__ __forceinline__ float fast_exp2(float xv) {
#if __has_builtin(__builtin_amdgcn_exp2f)
  return __builtin_amdgcn_exp2f(xv);
#else
  return exp2f(xv);
#endif
}

// ---------------- kernel 1: BN+ReLU stream + depthwise-conv half ----------------
// grid = 8192 (b=128 x m=64 row-quads), block = 256 (4 waves).
// Stages xb rows 4m..4m+3 (all 256 d) in LDS fp32, writes xbN bf16 to ws, and computes
// conv output rows C = 64w + m (wave w uses col-slice 64w..64w+63 of all 4 patch rows).
// Pure streaming: read 4KB fp32, write 2KB bf16 + 2KB fp32 out, ~80 VALU/thread.
__global__ __launch_bounds__(256) void bnconv_kernel(
    const float* __restrict__ x,
    const float* __restrict__ bn_gamma, const float* __restrict__ bn_beta,
    const float* __restrict__ bn_mean, const float* __restrict__ bn_var,
    const float* __restrict__ w_qkv, const float* __restrict__ w_qs,
    const float* __restrict__ w_ks,
    float* __restrict__ out, bf16* __restrict__ xbN)
{
  __shared__ float X[4][257];
  const int t   = threadIdx.x;
  const int b   = blockIdx.x >> 6;
  const int m   = blockIdx.x & 63;
  const int row = t >> 6;          // patch row 0..3 (staging role)
  const int l   = t & 63;
  const int n   = 4*m + row;

  float inv = rsqrtf(bn_var[n] + 1e-5f);
  float sc  = bn_gamma[n] * inv;
  float bs  = bn_beta[n] - bn_mean[n] * sc;
  float4 v  = *(const float4*)(x + ((size_t)b*256 + n)*256 + 4*l);
  float x0 = fmaxf(fmaf(v.x, sc, bs), 0.f);
  float x1 = fmaxf(fmaf(v.y, sc, bs), 0.f);
  float x2 = fmaxf(fmaf(v.z, sc, bs), 0.f);
  float x3 = fmaxf(fmaf(v.w, sc, bs), 0.f);
  X[row][4*l+0] = x0; X[row][4*l+1] = x1;
  X[row][4*l+2] = x2; X[row][4*l+3] = x3;
  bf16x4 bv; bv.x = (bf16)x0; bv.y = (bf16)x1; bv.z = (bf16)x2; bv.w = (bf16)x3;
  *(bf16x4*)(xbN + ((size_t)b*256 + n)*256 + 4*l) = bv;
  __syncthreads();

  // conv: wave wv computes output row C = 64*wv + m; lane l covers p = 4l..4l+3
  const int wv = row;
  const int C  = 64*wv + m;
  const int eo = 64*wv;
  float qs0 = w_qs[C*3+0], qs1 = w_qs[C*3+1], qs2 = w_qs[C*3+2];
  float ks0 = w_ks[C*3+0], ks1 = w_ks[C*3+1], ks2 = w_ks[C*3+2];
  float wq1r[4], wkc[4], wv1r[4], wkm[4], wkp[4];
#pragma unroll
  for (int r = 0; r < 4; ++r) {
    int a = 4*m + r;
    wq1r[r] = w_qkv[a*6+1];
    float wk = w_qkv[a*6+3];
    wv1r[r] = fmaf(ks1, wk, w_qkv[a*6+5]);  // center k-tap folded with v
    wkm[r]  = ks0 * wk;
    wkp[r]  = ks2 * wk;
  }
  (void)wkc;

  float res[2];
  float prev = 0.f;
#pragma unroll
  for (int pp = 0; pp < 4; ++pp) {
    int p  = 4*l + pp;
    int lr = p >> 6, e = p & 63, ww = p & 15;
    float fc = X[lr][eo + e];
    float qv = qs1 * fc;
    if (ww > 0)  qv = fmaf(qs0, X[lr][eo + e - 1], qv);
    if (ww < 15) qv = fmaf(qs2, X[lr][eo + e + 1], qv);
    float acc = fmaf(wq1r[lr], qv, wv1r[lr] * fc);
    if (p >= 16) {
      int pm = p - 16, lm = pm >> 6;
      acc = fmaf(wkm[lm], X[lm][eo + (pm & 63)], acc);
    }
    if (p < 240) {
      int pq = p + 16, lp = pq >> 6;
      acc = fmaf(wkp[lp], X[lp][eo + (pq & 63)], acc);
    }
    if (pp & 1) res[pp >> 1] = 0.5f * (prev + acc);
    else        prev = acc;
  }
  float2 o2; o2.x = res[0]; o2.y = res[1];
  *(float2*)(out + ((size_t)b*256 + C)*256 + 128 + 2*l) = o2;
}

// ---------------- kernel 2: attention (heads 0-3) ----------------
// grid = 512 (b x h), block = 512 (8 waves; wave w owns i-rows 32w..32w+31).
// Reads bf16 xbN slice (no BN math, half the staging bytes, L2/L3-warm from k1).
// R4 j-permuted symmetric S trick + R6 folded-cq / ones-MFMA rowsum retained.
// smem: Abf[256][72] @0 (36864) | VtF[64][264] @36864 (33792) | ckA @70656 | cvA @71680.
__global__ __launch_bounds__(512, 4) void attn_kernel(
    const bf16* __restrict__ xbN, const float* __restrict__ w_qkv,
    float* __restrict__ out)
{
  __shared__ __align__(16) char smem[72704];
  bf16 (*Abf)[72]  = (bf16(*)[72])smem;
  bf16 (*VtF)[264] = (bf16(*)[264])(smem + 36864);
  float* ckA = (float*)(smem + 70656);
  float* cvA = (float*)(smem + 71680);

  const int t  = threadIdx.x;
  const int bb = blockIdx.x >> 2;
  const int h  = blockIdx.x & 3;

  if (t < 256) {
    ckA[t] = w_qkv[t*6+2];
    cvA[t] = w_qkv[t*6+4];
  }

  // stage A slice (bf16, no conversion): 4 iters x 512 thr x 16B
  {
    const bf16* src = xbN + (size_t)bb * 65536 + h * 64;
#pragma unroll
    for (int it = 0; it < 4; ++it) {
      int idx = it*512 + t;
      int n = idx >> 3, ch = idx & 7;
      *(bf16x8*)&Abf[n][ch*8] = *(const bf16x8*)(src + (size_t)n*256 + ch*8);
    }
  }
  __syncthreads();   // Abf + ckA/cvA ready

  // build full V^T with cv folded: VtF[e][j] = cv[j] * A[j][e]; b32 writes (j-pairs)
  {
    const int J  = t & 127;
    const int eg = t >> 7;
    const bf16* r0 = &Abf[2*J][16*eg];
    const bf16* r1 = &Abf[2*J + 1][16*eg];
    bf16x8 a0l = *(const bf16x8*)r0, a0h = *(const bf16x8*)(r0 + 8);
    bf16x8 a1l = *(const bf16x8*)r1, a1h = *(const bf16x8*)(r1 + 8);
    float cv0 = cvA[2*J], cv1 = cvA[2*J + 1];
#pragma unroll
    for (int e = 0; e < 8; ++e) {
      union { bf16x2 hh; unsigned u; } wl, wh;
      wl.hh = (bf16x2){(bf16)((float)a0l[e]*cv0), (bf16)((float)a1l[e]*cv1)};
      wh.hh = (bf16x2){(bf16)((float)a0h[e]*cv0), (bf16)((float)a1h[e]*cv1)};
      *(unsigned*)&VtF[16*eg + e][2*J]     = wl.u;
      *(unsigned*)&VtF[16*eg + 8 + e][2*J] = wh.u;
    }
  }
  __syncthreads();

  const int lane = t & 63;
  const int wid  = t >> 6;
  const int q    = lane >> 4;
  const int c    = lane & 15;
  const int R    = wid * 32;
  const int jp   = ((c >> 2) << 3) + (c & 3);   // permuted j-row offset for A-op

  // B-operand (i-row) fragments, pre-scaled by cq_i * SCALE * log2(e)
  float cqs[2];
  cqs[0] = w_qkv[(R + c)*6]      * 0.18033688f;
  cqs[1] = w_qkv[(R + 16 + c)*6] * 0.18033688f;
  bf16x8 bi0[2], bi1[2];
#pragma unroll
  for (int it = 0; it < 2; ++it) {
    const bf16* bp = &Abf[R + 16*it + c][0];
    bf16x8 r0 = *(const bf16x8*)(bp + 8*q);
    bf16x8 r1 = *(const bf16x8*)(bp + 32 + 8*q);
#pragma unroll
    for (int e = 0; e < 8; ++e) {
      bi0[it][e] = (bf16)((float)r0[e] * cqs[it]);
      bi1[it][e] = (bf16)((float)r1[e] * cqs[it]);
    }
  }

  bf16x8 vbONE;
#pragma unroll
  for (int e = 0; e < 8; ++e) vbONE[e] = (bf16)1.0f;

  floatx4 oacc[2][4];
  floatx4 oaccL[2];
#pragma unroll
  for (int it = 0; it < 2; ++it) {
    oaccL[it] = (floatx4){0.f,0.f,0.f,0.f};
#pragma unroll
    for (int et = 0; et < 4; ++et)
      oacc[it][et] = (floatx4){0.f,0.f,0.f,0.f};
  }

  const int jbase = wid & 7;   // wave-staggered jt ring
#pragma unroll 2
  for (int jt = 0; jt < 8; ++jt) {
    const int j0 = (((jt + jbase) & 7) << 5);

    bf16x8 vb0 = *(const bf16x8*)&VtF[     c][j0 + 8*q];
    bf16x8 vb1 = *(const bf16x8*)&VtF[16 + c][j0 + 8*q];
    bf16x8 vb2 = *(const bf16x8*)&VtF[32 + c][j0 + 8*q];
    bf16x8 vb3 = *(const bf16x8*)&VtF[48 + c][j0 + 8*q];

    const int jr = j0 + jp;
    bf16x8 aj00 = *(const bf16x8*)&Abf[jr][8*q];
    bf16x8 aj01 = *(const bf16x8*)&Abf[jr][32 + 8*q];
    bf16x8 aj10 = *(const bf16x8*)&Abf[jr + 4][8*q];
    bf16x8 aj11 = *(const bf16x8*)&Abf[jr + 4][32 + 8*q];
    floatx4 ck0 = *(const floatx4*)&ckA[j0 + 8*q];
    floatx4 ck1 = *(const floatx4*)&ckA[j0 + 8*q + 4];

    bf16x8 pa[2];
#pragma unroll
    for (int it = 0; it < 2; ++it) {
      floatx4 s0 = (floatx4){0.f,0.f,0.f,0.f};
      floatx4 s1 = (floatx4){0.f,0.f,0.f,0.f};
      s0 = MFMA16(aj00, bi0[it], s0); s0 = MFMA16(aj01, bi1[it], s0);
      s1 = MFMA16(aj10, bi0[it], s1); s1 = MFMA16(aj11, bi1[it], s1);
      bf16x8 pv;
#pragma unroll
      for (int r = 0; r < 4; ++r) {
        pv[r]     = (bf16)fast_exp2(ck0[r] * s0[r]);
        pv[4 + r] = (bf16)fast_exp2(ck1[r] * s1[r]);
      }
      pa[it] = pv;
    }

    oaccL[0] = MFMA16(pa[0], vbONE, oaccL[0]);
    oaccL[1] = MFMA16(pa[1], vbONE, oaccL[1]);

    oacc[0][0] = MFMA16(pa[0], vb0, oacc[0][0]);
    oacc[1][0] = MFMA16(pa[1], vb0, oacc[1][0]);
    oacc[0][1] = MFMA16(pa[0], vb1, oacc[0][1]);
    oacc[1][1] = MFMA16(pa[1], vb1, oacc[1][1]);
    oacc[0][2] = MFMA16(pa[0], vb2, oacc[0][2]);
    oacc[1][2] = MFMA16(pa[1], vb2, oacc[1][2]);
    oacc[0][3] = MFMA16(pa[0], vb3, oacc[0][3]);
    oacc[1][3] = MFMA16(pa[1], vb3, oacc[1][3]);
  }

  float* outA = out + ((size_t)bb*256)*256 + h*32;
#pragma unroll
  for (int it = 0; it < 2; ++it) {
#pragma unroll
    for (int r = 0; r < 4; ++r) {
      float linv = 0.5f / oaccL[it][r];            // fold pair-average 0.5
      int n = R + 16*it + 4*q + r;
#pragma unroll
      for (int et = 0; et < 4; ++et) {
        float v = oacc[it][et][r];
        float v2 = v + __shfl_xor(v, 1, 64);
        if (!(lane & 1))
          outA[(size_t)n*256 + 8*et + (c>>1)] = v2 * linv;
      }
    }
  }
}

extern "C" void kernel_launch(void* const* d_in, const int* in_sizes, int n_in,
                              void* d_out, int out_size, void* d_ws, size_t ws_size,
                              hipStream_t stream) {
  (void)in_sizes; (void)n_in; (void)out_size; (void)ws_size;
  const float* x    = (const float*)d_in[0];
  const float* g    = (const float*)d_in[1];
  const float* be   = (const float*)d_in[2];
  const float* mn   = (const float*)d_in[3];
  const float* vr   = (const float*)d_in[4];
  const float* wqkv = (const float*)d_in[5];
  const float* wqs  = (const float*)d_in[6];
  const float* wks  = (const float*)d_in[7];
  float* out = (float*)d_out;
  bf16* xbN  = (bf16*)d_ws;   // 128*256*256 bf16 = 33.5 MB

  bnconv_kernel<<<dim3(8192), dim3(256), 0, stream>>>(x, g, be, mn, vr, wqkv, wqs, wks,
                                                      out, xbN);
  attn_kernel<<<dim3(512), dim3(512), 0, stream>>>(xbN, wqkv, out);
}